// Round 1
// baseline (892.427 us; speedup 1.0000x reference)
//
#include <hip/hip_runtime.h>

#define NN 100000
#define NE 1600000

// ---------------- CSR build ----------------

__global__ __launch_bounds__(256) void hist_kernel(const int* __restrict__ dst,
                                                   int* __restrict__ deg, int E) {
    int e = blockIdx.x * 256 + threadIdx.x;
    if (e < E) atomicAdd(&deg[dst[e]], 1);
}

__global__ __launch_bounds__(1024) void scan_kernel(const int* __restrict__ deg,
                                                    int* __restrict__ offsets,
                                                    int* __restrict__ cursor, int N) {
    __shared__ int sums[1024];
    int t = threadIdx.x;
    int chunk = (N + 1023) >> 10;
    int lo = t * chunk;
    int hi = min(lo + chunk, N);
    int s = 0;
    for (int i = lo; i < hi; ++i) s += deg[i];
    sums[t] = s;
    __syncthreads();
    // Hillis-Steele inclusive scan over 1024 partials
    for (int off = 1; off < 1024; off <<= 1) {
        int v = (t >= off) ? sums[t - off] : 0;
        __syncthreads();
        sums[t] += v;
        __syncthreads();
    }
    int base = (t == 0) ? 0 : sums[t - 1];
    for (int i = lo; i < hi; ++i) {
        offsets[i] = base;
        cursor[i]  = base;
        base += deg[i];
    }
    if (t == 1023) offsets[N] = sums[1023];
}

__global__ __launch_bounds__(256) void scatter_kernel(const int* __restrict__ src,
                                                      const int* __restrict__ dst,
                                                      const float* __restrict__ w,
                                                      int* __restrict__ cursor,
                                                      int* __restrict__ csr_src,
                                                      float* __restrict__ csr_w, int E) {
    int e = blockIdx.x * 256 + threadIdx.x;
    if (e >= E) return;
    int d = dst[e];
    int slot = atomicAdd(&cursor[d], 1);
    csr_src[slot] = src[e];
    csr_w[slot]   = w[e];
}

// ---------------- dense GEMM: S[N,64] = X[N,K] @ W[K,64] ----------------
// one wave per row; lane = output column; W transposed in LDS, +1 pad
// (bank = (129*j + k) % 32 = (j+k)%32 -> 2-way across 64 lanes = free)

template <int K>
__global__ __launch_bounds__(256) void gemm_kernel(const float* __restrict__ X,
                                                   const float* __restrict__ W,
                                                   float* __restrict__ S, int N) {
    __shared__ float Wt[64][K + 1];
    for (int idx = threadIdx.x; idx < K * 64; idx += 256) {
        int k = idx >> 6, j = idx & 63;
        Wt[j][k] = W[idx];
    }
    __syncthreads();

    int wave = threadIdx.x >> 6;
    int lane = threadIdx.x & 63;
    int row  = blockIdx.x * 4 + wave;
    if (row >= N) return;

    const float* x = X + (size_t)row * K;
    float acc = 0.f;
#pragma unroll 8
    for (int k = 0; k < K; k += 4) {
        float4 xv = *reinterpret_cast<const float4*>(x + k);  // lane-uniform, broadcast
        acc += xv.x * Wt[lane][k]     + xv.y * Wt[lane][k + 1]
             + xv.z * Wt[lane][k + 2] + xv.w * Wt[lane][k + 3];
    }
    S[(size_t)row * 64 + lane] = acc;
}

// ---------------- SPMM gather: out[r,:] = sum_e w_e * S[src_e,:] + b ----------------
// one wave per dst row, lane = column, zero atomics

template <bool RELU>
__global__ __launch_bounds__(256) void spmm_kernel(const int* __restrict__ csr_src,
                                                   const float* __restrict__ csr_w,
                                                   const int* __restrict__ offsets,
                                                   const float* __restrict__ S,
                                                   const float* __restrict__ bias,
                                                   float* __restrict__ out, int N) {
    int wave = threadIdx.x >> 6;
    int lane = threadIdx.x & 63;
    int row  = blockIdx.x * 4 + wave;
    if (row >= N) return;

    int beg = offsets[row];
    int end = offsets[row + 1];
    float acc = 0.f;
    int e = beg;
    for (; e + 4 <= end; e += 4) {
        int   s0 = csr_src[e],     s1 = csr_src[e + 1],
              s2 = csr_src[e + 2], s3 = csr_src[e + 3];
        float w0 = csr_w[e],     w1 = csr_w[e + 1],
              w2 = csr_w[e + 2], w3 = csr_w[e + 3];
        float v0 = S[s0 * 64 + lane];
        float v1 = S[s1 * 64 + lane];
        float v2 = S[s2 * 64 + lane];
        float v3 = S[s3 * 64 + lane];
        acc += w0 * v0;
        acc += w1 * v1;
        acc += w2 * v2;
        acc += w3 * v3;
    }
    for (; e < end; ++e) {
        acc += csr_w[e] * S[csr_src[e] * 64 + lane];
    }
    float v = acc + bias[lane];
    if (RELU) v = fmaxf(v, 0.f);
    out[(size_t)row * 64 + lane] = v;
}

// ---------------- launch ----------------

extern "C" void kernel_launch(void* const* d_in, const int* in_sizes, int n_in,
                              void* d_out, int out_size, void* d_ws, size_t ws_size,
                              hipStream_t stream) {
    const float* features = (const float*)d_in[0];
    const int*   src      = (const int*)d_in[1];
    const int*   dst      = (const int*)d_in[2];
    const float* ew       = (const float*)d_in[3];
    const float* W1       = (const float*)d_in[4];
    const float* b1       = (const float*)d_in[5];
    const float* W2       = (const float*)d_in[6];
    const float* b2       = (const float*)d_in[7];
    const float* W3       = (const float*)d_in[8];
    const float* b3       = (const float*)d_in[9];
    float*       out      = (float*)d_out;

    // workspace layout (~65.2 MB)
    float* s_buf   = (float*)d_ws;                    // NN*64 f32
    float* h_buf   = s_buf + (size_t)NN * 64;         // NN*64 f32
    int*   deg     = (int*)(h_buf + (size_t)NN * 64); // NN
    int*   offsets = deg + NN;                        // NN+1
    int*   cursor  = offsets + NN + 1;                // NN
    int*   csr_src = cursor + NN;                     // NE
    float* csr_w   = (float*)(csr_src + NE);          // NE

    hipMemsetAsync(deg, 0, NN * sizeof(int), stream);
    hist_kernel<<<(NE + 255) / 256, 256, 0, stream>>>(dst, deg, NE);
    scan_kernel<<<1, 1024, 0, stream>>>(deg, offsets, cursor, NN);
    scatter_kernel<<<(NE + 255) / 256, 256, 0, stream>>>(src, dst, ew, cursor,
                                                         csr_src, csr_w, NE);

    int grid_rows = (NN + 3) / 4;
    gemm_kernel<128><<<grid_rows, 256, 0, stream>>>(features, W1, s_buf, NN);
    spmm_kernel<true><<<grid_rows, 256, 0, stream>>>(csr_src, csr_w, offsets, s_buf, b1, h_buf, NN);
    gemm_kernel<64><<<grid_rows, 256, 0, stream>>>(h_buf, W2, s_buf, NN);
    spmm_kernel<true><<<grid_rows, 256, 0, stream>>>(csr_src, csr_w, offsets, s_buf, b2, h_buf, NN);
    gemm_kernel<64><<<grid_rows, 256, 0, stream>>>(h_buf, W3, s_buf, NN);
    spmm_kernel<false><<<grid_rows, 256, 0, stream>>>(csr_src, csr_w, offsets, s_buf, b3, out, NN);
}

// Round 2
// 669.131 us; speedup vs baseline: 1.3337x; 1.3337x over previous
//
#include <hip/hip_runtime.h>

#define NN 100000
#define NE 1600000

#define SCAN_ELEMS 1024
#define SCAN_NB ((NN + SCAN_ELEMS - 1) / SCAN_ELEMS)   // 98

// ---------------- CSR build ----------------

__global__ __launch_bounds__(256) void hist_kernel(const int* __restrict__ dst,
                                                   int* __restrict__ deg) {
    int e4 = (blockIdx.x * 256 + threadIdx.x) * 4;
    if (e4 >= NE) return;
    int4 d = *reinterpret_cast<const int4*>(dst + e4);
    atomicAdd(&deg[d.x], 1);
    atomicAdd(&deg[d.y], 1);
    atomicAdd(&deg[d.z], 1);
    atomicAdd(&deg[d.w], 1);
}

// pass1: per-block (1024-elem) sums
__global__ __launch_bounds__(256) void scan_pass1(const int* __restrict__ deg,
                                                  int* __restrict__ bsum) {
    int t = threadIdx.x;
    int i4 = blockIdx.x * SCAN_ELEMS + t * 4;
    int s = 0;
    if (i4 < NN) {  // NN % 4 == 0 -> whole int4 valid
        int4 v = *reinterpret_cast<const int4*>(deg + i4);
        s = v.x + v.y + v.z + v.w;
    }
    __shared__ int red[256];
    red[t] = s;
    __syncthreads();
    for (int off = 128; off > 0; off >>= 1) {
        if (t < off) red[t] += red[t + off];
        __syncthreads();
    }
    if (t == 0) bsum[blockIdx.x] = red[0];
}

// pass2: single small block scans the 98 partials -> exclusive; writes offsets[NN]
__global__ __launch_bounds__(128) void scan_pass2(int* __restrict__ bsum,
                                                  int* __restrict__ offsets) {
    int t = threadIdx.x;
    int v = (t < SCAN_NB) ? bsum[t] : 0;
    __shared__ int tmp[128];
    tmp[t] = v;
    __syncthreads();
    for (int off = 1; off < 128; off <<= 1) {
        int u = (t >= off) ? tmp[t - off] : 0;
        __syncthreads();
        tmp[t] += u;
        __syncthreads();
    }
    if (t < SCAN_NB) bsum[t] = tmp[t] - v;          // exclusive block base
    if (t == SCAN_NB - 1) offsets[NN] = tmp[t];     // grand total
}

// pass3: local exclusive scan + block base -> offsets & cursor
__global__ __launch_bounds__(256) void scan_pass3(const int* __restrict__ deg,
                                                  const int* __restrict__ bsum,
                                                  int* __restrict__ offsets,
                                                  int* __restrict__ cursor) {
    int t = threadIdx.x;
    int i4 = blockIdx.x * SCAN_ELEMS + t * 4;
    int4 v = make_int4(0, 0, 0, 0);
    if (i4 < NN) v = *reinterpret_cast<const int4*>(deg + i4);
    int s = v.x + v.y + v.z + v.w;
    __shared__ int tmp[256];
    tmp[t] = s;
    __syncthreads();
    for (int off = 1; off < 256; off <<= 1) {
        int u = (t >= off) ? tmp[t - off] : 0;
        __syncthreads();
        tmp[t] += u;
        __syncthreads();
    }
    if (i4 < NN) {
        int base = bsum[blockIdx.x] + tmp[t] - s;   // exclusive prefix of this int4
        int4 o;
        o.x = base;
        o.y = o.x + v.x;
        o.z = o.y + v.y;
        o.w = o.z + v.z;
        *reinterpret_cast<int4*>(offsets + i4) = o;
        *reinterpret_cast<int4*>(cursor + i4) = o;
    }
}

// scatter: one packed 8B record per edge (random slot) instead of 2x4B
__global__ __launch_bounds__(256) void scatter_kernel(const int* __restrict__ src,
                                                      const int* __restrict__ dst,
                                                      const float* __restrict__ w,
                                                      int* __restrict__ cursor,
                                                      int2* __restrict__ csr) {
    int e4 = (blockIdx.x * 256 + threadIdx.x) * 4;
    if (e4 >= NE) return;
    int4   s = *reinterpret_cast<const int4*>(src + e4);
    int4   d = *reinterpret_cast<const int4*>(dst + e4);
    float4 ww = *reinterpret_cast<const float4*>(w + e4);
    int slot;
    slot = atomicAdd(&cursor[d.x], 1); csr[slot] = make_int2(s.x, __float_as_int(ww.x));
    slot = atomicAdd(&cursor[d.y], 1); csr[slot] = make_int2(s.y, __float_as_int(ww.y));
    slot = atomicAdd(&cursor[d.z], 1); csr[slot] = make_int2(s.z, __float_as_int(ww.z));
    slot = atomicAdd(&cursor[d.w], 1); csr[slot] = make_int2(s.w, __float_as_int(ww.w));
}

// ---------------- dense GEMM: S[N,64] = X[N,K] @ W[K,64] ----------------

template <int K>
__global__ __launch_bounds__(256) void gemm_kernel(const float* __restrict__ X,
                                                   const float* __restrict__ W,
                                                   float* __restrict__ S, int N) {
    __shared__ float Wt[64][K + 1];
    for (int idx = threadIdx.x; idx < K * 64; idx += 256) {
        int k = idx >> 6, j = idx & 63;
        Wt[j][k] = W[idx];
    }
    __syncthreads();

    int wave = threadIdx.x >> 6;
    int lane = threadIdx.x & 63;
    int row  = blockIdx.x * 4 + wave;
    if (row >= N) return;

    const float* x = X + (size_t)row * K;
    float acc = 0.f;
#pragma unroll 8
    for (int k = 0; k < K; k += 4) {
        float4 xv = *reinterpret_cast<const float4*>(x + k);  // lane-uniform broadcast
        acc += xv.x * Wt[lane][k]     + xv.y * Wt[lane][k + 1]
             + xv.z * Wt[lane][k + 2] + xv.w * Wt[lane][k + 3];
    }
    S[(size_t)row * 64 + lane] = acc;
}

// ---------------- SPMM gather ----------------

template <bool RELU>
__global__ __launch_bounds__(256) void spmm_kernel(const int2* __restrict__ csr,
                                                   const int* __restrict__ offsets,
                                                   const float* __restrict__ S,
                                                   const float* __restrict__ bias,
                                                   float* __restrict__ out, int N) {
    int wave = threadIdx.x >> 6;
    int lane = threadIdx.x & 63;
    int row  = blockIdx.x * 4 + wave;
    if (row >= N) return;

    int beg = offsets[row];
    int end = offsets[row + 1];
    float acc = 0.f;
    int e = beg;
    for (; e + 4 <= end; e += 4) {
        int2 e0 = csr[e],     e1 = csr[e + 1];
        int2 e2 = csr[e + 2], e3 = csr[e + 3];
        float v0 = S[e0.x * 64 + lane];
        float v1 = S[e1.x * 64 + lane];
        float v2 = S[e2.x * 64 + lane];
        float v3 = S[e3.x * 64 + lane];
        acc += __int_as_float(e0.y) * v0;
        acc += __int_as_float(e1.y) * v1;
        acc += __int_as_float(e2.y) * v2;
        acc += __int_as_float(e3.y) * v3;
    }
    for (; e < end; ++e) {
        int2 ee = csr[e];
        acc += __int_as_float(ee.y) * S[ee.x * 64 + lane];
    }
    float v = acc + bias[lane];
    if (RELU) v = fmaxf(v, 0.f);
    out[(size_t)row * 64 + lane] = v;
}

// ---------------- launch ----------------

extern "C" void kernel_launch(void* const* d_in, const int* in_sizes, int n_in,
                              void* d_out, int out_size, void* d_ws, size_t ws_size,
                              hipStream_t stream) {
    const float* features = (const float*)d_in[0];
    const int*   src      = (const int*)d_in[1];
    const int*   dst      = (const int*)d_in[2];
    const float* ew       = (const float*)d_in[3];
    const float* W1       = (const float*)d_in[4];
    const float* b1       = (const float*)d_in[5];
    const float* W2       = (const float*)d_in[6];
    const float* b2       = (const float*)d_in[7];
    const float* W3       = (const float*)d_in[8];
    const float* b3       = (const float*)d_in[9];
    float*       out      = (float*)d_out;

    // workspace layout (all segments 16B-aligned)
    float* s_buf   = (float*)d_ws;                     // NN*64 f32
    float* h_buf   = s_buf + (size_t)NN * 64;          // NN*64 f32
    int*   deg     = (int*)(h_buf + (size_t)NN * 64);  // NN
    int*   offsets = deg + NN;                         // NN+4 (padded for alignment)
    int*   cursor  = offsets + NN + 4;                 // NN
    int*   bsum    = cursor + NN;                      // SCAN_NB (pad to 128)
    int2*  csr     = (int2*)(bsum + 128);              // NE packed records

    hipMemsetAsync(deg, 0, NN * sizeof(int), stream);
    hist_kernel<<<(NE / 4 + 255) / 256, 256, 0, stream>>>(dst, deg);
    scan_pass1<<<SCAN_NB, 256, 0, stream>>>(deg, bsum);
    scan_pass2<<<1, 128, 0, stream>>>(bsum, offsets);
    scan_pass3<<<SCAN_NB, 256, 0, stream>>>(deg, bsum, offsets, cursor);
    scatter_kernel<<<(NE / 4 + 255) / 256, 256, 0, stream>>>(src, dst, ew, cursor, csr);

    int grid_rows = (NN + 3) / 4;
    gemm_kernel<128><<<grid_rows, 256, 0, stream>>>(features, W1, s_buf, NN);
    spmm_kernel<true><<<grid_rows, 256, 0, stream>>>(csr, offsets, s_buf, b1, h_buf, NN);
    gemm_kernel<64><<<grid_rows, 256, 0, stream>>>(h_buf, W2, s_buf, NN);
    spmm_kernel<true><<<grid_rows, 256, 0, stream>>>(csr, offsets, s_buf, b2, h_buf, NN);
    gemm_kernel<64><<<grid_rows, 256, 0, stream>>>(h_buf, W3, s_buf, NN);
    spmm_kernel<false><<<grid_rows, 256, 0, stream>>>(csr, offsets, s_buf, b3, out, NN);
}

// Round 3
// 502.775 us; speedup vs baseline: 1.7750x; 1.3309x over previous
//
#include <hip/hip_runtime.h>

#define NN 100000
#define NE 1600000

#define SCAN_ELEMS 1024
#define SCAN_NB ((NN + SCAN_ELEMS - 1) / SCAN_ELEMS)   // 98

// ---------------- CSR build ----------------

__global__ __launch_bounds__(256) void hist_kernel(const int* __restrict__ dst,
                                                   int* __restrict__ deg) {
    int e4 = (blockIdx.x * 256 + threadIdx.x) * 4;
    if (e4 >= NE) return;
    int4 d = *reinterpret_cast<const int4*>(dst + e4);
    atomicAdd(&deg[d.x], 1);
    atomicAdd(&deg[d.y], 1);
    atomicAdd(&deg[d.z], 1);
    atomicAdd(&deg[d.w], 1);
}

__global__ __launch_bounds__(256) void scan_pass1(const int* __restrict__ deg,
                                                  int* __restrict__ bsum) {
    int t = threadIdx.x;
    int i4 = blockIdx.x * SCAN_ELEMS + t * 4;
    int s = 0;
    if (i4 < NN) {
        int4 v = *reinterpret_cast<const int4*>(deg + i4);
        s = v.x + v.y + v.z + v.w;
    }
    __shared__ int red[256];
    red[t] = s;
    __syncthreads();
    for (int off = 128; off > 0; off >>= 1) {
        if (t < off) red[t] += red[t + off];
        __syncthreads();
    }
    if (t == 0) bsum[blockIdx.x] = red[0];
}

__global__ __launch_bounds__(128) void scan_pass2(int* __restrict__ bsum,
                                                  int* __restrict__ offsets) {
    int t = threadIdx.x;
    int v = (t < SCAN_NB) ? bsum[t] : 0;
    __shared__ int tmp[128];
    tmp[t] = v;
    __syncthreads();
    for (int off = 1; off < 128; off <<= 1) {
        int u = (t >= off) ? tmp[t - off] : 0;
        __syncthreads();
        tmp[t] += u;
        __syncthreads();
    }
    if (t < SCAN_NB) bsum[t] = tmp[t] - v;
    if (t == SCAN_NB - 1) offsets[NN] = tmp[t];
}

__global__ __launch_bounds__(256) void scan_pass3(const int* __restrict__ deg,
                                                  const int* __restrict__ bsum,
                                                  int* __restrict__ offsets,
                                                  int* __restrict__ cursor) {
    int t = threadIdx.x;
    int i4 = blockIdx.x * SCAN_ELEMS + t * 4;
    int4 v = make_int4(0, 0, 0, 0);
    if (i4 < NN) v = *reinterpret_cast<const int4*>(deg + i4);
    int s = v.x + v.y + v.z + v.w;
    __shared__ int tmp[256];
    tmp[t] = s;
    __syncthreads();
    for (int off = 1; off < 256; off <<= 1) {
        int u = (t >= off) ? tmp[t - off] : 0;
        __syncthreads();
        tmp[t] += u;
        __syncthreads();
    }
    if (i4 < NN) {
        int base = bsum[blockIdx.x] + tmp[t] - s;
        int4 o;
        o.x = base;
        o.y = o.x + v.x;
        o.z = o.y + v.y;
        o.w = o.z + v.z;
        *reinterpret_cast<int4*>(offsets + i4) = o;
        *reinterpret_cast<int4*>(cursor + i4) = o;
    }
}

__global__ __launch_bounds__(256) void scatter_kernel(const int* __restrict__ src,
                                                      const int* __restrict__ dst,
                                                      const float* __restrict__ w,
                                                      int* __restrict__ cursor,
                                                      int2* __restrict__ csr) {
    int e4 = (blockIdx.x * 256 + threadIdx.x) * 4;
    if (e4 >= NE) return;
    int4   s = *reinterpret_cast<const int4*>(src + e4);
    int4   d = *reinterpret_cast<const int4*>(dst + e4);
    float4 ww = *reinterpret_cast<const float4*>(w + e4);
    int slot;
    slot = atomicAdd(&cursor[d.x], 1); csr[slot] = make_int2(s.x, __float_as_int(ww.x));
    slot = atomicAdd(&cursor[d.y], 1); csr[slot] = make_int2(s.y, __float_as_int(ww.y));
    slot = atomicAdd(&cursor[d.z], 1); csr[slot] = make_int2(s.z, __float_as_int(ww.z));
    slot = atomicAdd(&cursor[d.w], 1); csr[slot] = make_int2(s.w, __float_as_int(ww.w));
}

// ---------------- dense GEMM: S[N,64] = X[N,K] @ W[K,64] ----------------
// 8 rows per wave: W LDS read amortized 8x (was the LDS-issue bottleneck).
// row0 forced uniform via readfirstlane -> x loads become s_load (SMEM pipe).
// Wt[64][K+1]: bank = (j+k)%32 across lanes -> 2-way aliasing = free.

template <int K>
__global__ __launch_bounds__(256) void gemm_kernel(const float* __restrict__ X,
                                                   const float* __restrict__ W,
                                                   float* __restrict__ S) {
    __shared__ float Wt[64][K + 1];
    for (int idx = threadIdx.x; idx < K * 64; idx += 256) {
        int k = idx >> 6, j = idx & 63;
        Wt[j][k] = W[idx];
    }
    __syncthreads();

    int wave = threadIdx.x >> 6;
    int lane = threadIdx.x & 63;
    int row0 = (blockIdx.x * 4 + wave) * 8;               // 8 rows per wave
    row0 = __builtin_amdgcn_readfirstlane(row0);          // force SGPR -> s_load for x

    const float* x0 = X + (size_t)row0 * K;
    float acc[8] = {0.f, 0.f, 0.f, 0.f, 0.f, 0.f, 0.f, 0.f};

#pragma unroll 4
    for (int k = 0; k < K; k += 4) {
        float w0 = Wt[lane][k];
        float w1 = Wt[lane][k + 1];
        float w2 = Wt[lane][k + 2];
        float w3 = Wt[lane][k + 3];
#pragma unroll
        for (int r = 0; r < 8; ++r) {
            float4 xv = *reinterpret_cast<const float4*>(x0 + r * K + k);  // uniform addr
            acc[r] += xv.x * w0 + xv.y * w1 + xv.z * w2 + xv.w * w3;
        }
    }
#pragma unroll
    for (int r = 0; r < 8; ++r) {
        S[(size_t)(row0 + r) * 64 + lane] = acc[r];
    }
}

// ---------------- SPMM gather ----------------

template <bool RELU>
__global__ __launch_bounds__(256) void spmm_kernel(const int2* __restrict__ csr,
                                                   const int* __restrict__ offsets,
                                                   const float* __restrict__ S,
                                                   const float* __restrict__ bias,
                                                   float* __restrict__ out, int N) {
    int wave = threadIdx.x >> 6;
    int lane = threadIdx.x & 63;
    int row  = blockIdx.x * 4 + wave;
    if (row >= N) return;

    int beg = offsets[row];
    int end = offsets[row + 1];
    float acc = 0.f;
    int e = beg;
    for (; e + 4 <= end; e += 4) {
        int2 e0 = csr[e],     e1 = csr[e + 1];
        int2 e2 = csr[e + 2], e3 = csr[e + 3];
        float v0 = S[e0.x * 64 + lane];
        float v1 = S[e1.x * 64 + lane];
        float v2 = S[e2.x * 64 + lane];
        float v3 = S[e3.x * 64 + lane];
        acc += __int_as_float(e0.y) * v0;
        acc += __int_as_float(e1.y) * v1;
        acc += __int_as_float(e2.y) * v2;
        acc += __int_as_float(e3.y) * v3;
    }
    for (; e < end; ++e) {
        int2 ee = csr[e];
        acc += __int_as_float(ee.y) * S[ee.x * 64 + lane];
    }
    float v = acc + bias[lane];
    if (RELU) v = fmaxf(v, 0.f);
    out[(size_t)row * 64 + lane] = v;
}

// ---------------- launch ----------------

extern "C" void kernel_launch(void* const* d_in, const int* in_sizes, int n_in,
                              void* d_out, int out_size, void* d_ws, size_t ws_size,
                              hipStream_t stream) {
    const float* features = (const float*)d_in[0];
    const int*   src      = (const int*)d_in[1];
    const int*   dst      = (const int*)d_in[2];
    const float* ew       = (const float*)d_in[3];
    const float* W1       = (const float*)d_in[4];
    const float* b1       = (const float*)d_in[5];
    const float* W2       = (const float*)d_in[6];
    const float* b2       = (const float*)d_in[7];
    const float* W3       = (const float*)d_in[8];
    const float* b3       = (const float*)d_in[9];
    float*       out      = (float*)d_out;

    float* s_buf   = (float*)d_ws;                     // NN*64 f32
    float* h_buf   = s_buf + (size_t)NN * 64;          // NN*64 f32
    int*   deg     = (int*)(h_buf + (size_t)NN * 64);  // NN
    int*   offsets = deg + NN;                         // NN+4
    int*   cursor  = offsets + NN + 4;                 // NN
    int*   bsum    = cursor + NN;                      // pad to 128
    int2*  csr     = (int2*)(bsum + 128);              // NE packed records

    hipMemsetAsync(deg, 0, NN * sizeof(int), stream);
    hist_kernel<<<(NE / 4 + 255) / 256, 256, 0, stream>>>(dst, deg);
    scan_pass1<<<SCAN_NB, 256, 0, stream>>>(deg, bsum);
    scan_pass2<<<1, 128, 0, stream>>>(bsum, offsets);
    scan_pass3<<<SCAN_NB, 256, 0, stream>>>(deg, bsum, offsets, cursor);
    scatter_kernel<<<(NE / 4 + 255) / 256, 256, 0, stream>>>(src, dst, ew, cursor, csr);

    int grid_gemm = NN / 32;  // 3125, exact: 32 rows per block
    int grid_rows = (NN + 3) / 4;
    gemm_kernel<128><<<grid_gemm, 256, 0, stream>>>(features, W1, s_buf);
    spmm_kernel<true><<<grid_rows, 256, 0, stream>>>(csr, offsets, s_buf, b1, h_buf, NN);
    gemm_kernel<64><<<grid_gemm, 256, 0, stream>>>(h_buf, W2, s_buf);
    spmm_kernel<true><<<grid_rows, 256, 0, stream>>>(csr, offsets, s_buf, b2, h_buf, NN);
    gemm_kernel<64><<<grid_gemm, 256, 0, stream>>>(h_buf, W3, s_buf);
    spmm_kernel<false><<<grid_rows, 256, 0, stream>>>(csr, offsets, s_buf, b3, out, NN);
}

// Round 5
// 473.508 us; speedup vs baseline: 1.8847x; 1.0618x over previous
//
#include <hip/hip_runtime.h>

#define NN 100000
#define NE 1600000

#define SCAN_ELEMS 1024
#define SCAN_NB ((NN + SCAN_ELEMS - 1) / SCAN_ELEMS)   // 98

#define NWIN 8
#define WIN_SZ (NN / NWIN)   // 12500

typedef int int4v __attribute__((ext_vector_type(4)));  // native vec for nontemporal builtins

// ---------------- CSR build ----------------

__global__ __launch_bounds__(256) void hist_kernel(const int* __restrict__ dst,
                                                   int* __restrict__ deg) {
    int e4 = (blockIdx.x * 256 + threadIdx.x) * 4;
    if (e4 >= NE) return;
    int4 d = *reinterpret_cast<const int4*>(dst + e4);
    atomicAdd(&deg[d.x], 1);
    atomicAdd(&deg[d.y], 1);
    atomicAdd(&deg[d.z], 1);
    atomicAdd(&deg[d.w], 1);
}

__global__ __launch_bounds__(256) void scan_pass1(const int* __restrict__ deg,
                                                  int* __restrict__ bsum) {
    int t = threadIdx.x;
    int i4 = blockIdx.x * SCAN_ELEMS + t * 4;
    int s = 0;
    if (i4 < NN) {
        int4 v = *reinterpret_cast<const int4*>(deg + i4);
        s = v.x + v.y + v.z + v.w;
    }
    __shared__ int red[256];
    red[t] = s;
    __syncthreads();
    for (int off = 128; off > 0; off >>= 1) {
        if (t < off) red[t] += red[t + off];
        __syncthreads();
    }
    if (t == 0) bsum[blockIdx.x] = red[0];
}

__global__ __launch_bounds__(128) void scan_pass2(int* __restrict__ bsum,
                                                  int* __restrict__ offsets) {
    int t = threadIdx.x;
    int v = (t < SCAN_NB) ? bsum[t] : 0;
    __shared__ int tmp[128];
    tmp[t] = v;
    __syncthreads();
    for (int off = 1; off < 128; off <<= 1) {
        int u = (t >= off) ? tmp[t - off] : 0;
        __syncthreads();
        tmp[t] += u;
        __syncthreads();
    }
    if (t < SCAN_NB) bsum[t] = tmp[t] - v;
    if (t == SCAN_NB - 1) offsets[NN] = tmp[t];
}

__global__ __launch_bounds__(256) void scan_pass3(const int* __restrict__ deg,
                                                  const int* __restrict__ bsum,
                                                  int* __restrict__ offsets,
                                                  int* __restrict__ cursor) {
    int t = threadIdx.x;
    int i4 = blockIdx.x * SCAN_ELEMS + t * 4;
    int4 v = make_int4(0, 0, 0, 0);
    if (i4 < NN) v = *reinterpret_cast<const int4*>(deg + i4);
    int s = v.x + v.y + v.z + v.w;
    __shared__ int tmp[256];
    tmp[t] = s;
    __syncthreads();
    for (int off = 1; off < 256; off <<= 1) {
        int u = (t >= off) ? tmp[t - off] : 0;
        __syncthreads();
        tmp[t] += u;
        __syncthreads();
    }
    if (i4 < NN) {
        int base = bsum[blockIdx.x] + tmp[t] - s;
        int4 o;
        o.x = base;
        o.y = o.x + v.x;
        o.z = o.y + v.y;
        o.w = o.z + v.z;
        *reinterpret_cast<int4*>(offsets + i4) = o;
        *reinterpret_cast<int4*>(cursor + i4) = o;
    }
}

// XCD-windowed scatter: window = blockIdx&7 pins each dst-window to one XCD
// (round-robin heuristic). All stores to a 64B CSR line then come from one
// XCD -> they merge in its L2 (window working set 1.6MB < 4MB) and evict
// once. Edge streams use nontemporal loads so they don't evict dirty lines.
__global__ __launch_bounds__(256) void scatter_kernel(const int* __restrict__ src,
                                                      const int* __restrict__ dst,
                                                      const float* __restrict__ w,
                                                      int* __restrict__ cursor,
                                                      int2* __restrict__ csr) {
    int win   = blockIdx.x & (NWIN - 1);
    int chunk = blockIdx.x >> 3;
    int e4 = (chunk * 256 + threadIdx.x) * 4;
    if (e4 >= NE) return;
    int4v d = __builtin_nontemporal_load(reinterpret_cast<const int4v*>(dst + e4));
    const int wlo = win * WIN_SZ;
#pragma unroll
    for (int i = 0; i < 4; ++i) {
        int di = d[i];
        if (di >= wlo && di < wlo + WIN_SZ) {
            int   s  = __builtin_nontemporal_load(src + e4 + i);
            float ww = __builtin_nontemporal_load(w + e4 + i);
            int slot = atomicAdd(&cursor[di], 1);
            csr[slot] = make_int2(s, __float_as_int(ww));
        }
    }
}

// ---------------- dense GEMM: S[N,64] = X[N,K] @ W[K,64] ----------------
// 8 rows per wave; W LDS reads amortized 8x; uniform x addr -> s_load.

template <int K>
__global__ __launch_bounds__(256) void gemm_kernel(const float* __restrict__ X,
                                                   const float* __restrict__ W,
                                                   float* __restrict__ S) {
    __shared__ float Wt[64][K + 1];
    for (int idx = threadIdx.x; idx < K * 64; idx += 256) {
        int k = idx >> 6, j = idx & 63;
        Wt[j][k] = W[idx];
    }
    __syncthreads();

    int wave = threadIdx.x >> 6;
    int lane = threadIdx.x & 63;
    int row0 = (blockIdx.x * 4 + wave) * 8;
    row0 = __builtin_amdgcn_readfirstlane(row0);

    const float* x0 = X + (size_t)row0 * K;
    float acc[8] = {0.f, 0.f, 0.f, 0.f, 0.f, 0.f, 0.f, 0.f};

#pragma unroll 4
    for (int k = 0; k < K; k += 4) {
        float w0 = Wt[lane][k];
        float w1 = Wt[lane][k + 1];
        float w2 = Wt[lane][k + 2];
        float w3 = Wt[lane][k + 3];
#pragma unroll
        for (int r = 0; r < 8; ++r) {
            float4 xv = *reinterpret_cast<const float4*>(x0 + r * K + k);
            acc[r] += xv.x * w0 + xv.y * w1 + xv.z * w2 + xv.w * w3;
        }
    }
#pragma unroll
    for (int r = 0; r < 8; ++r) {
        S[(size_t)(row0 + r) * 64 + lane] = acc[r];
    }
}

// ---------------- SPMM gather ----------------

template <bool RELU>
__global__ __launch_bounds__(256) void spmm_kernel(const int2* __restrict__ csr,
                                                   const int* __restrict__ offsets,
                                                   const float* __restrict__ S,
                                                   const float* __restrict__ bias,
                                                   float* __restrict__ out, int N) {
    int wave = threadIdx.x >> 6;
    int lane = threadIdx.x & 63;
    int row  = blockIdx.x * 4 + wave;
    if (row >= N) return;

    int beg = offsets[row];
    int end = offsets[row + 1];
    float acc = 0.f;
    int e = beg;
    for (; e + 4 <= end; e += 4) {
        int2 e0 = csr[e],     e1 = csr[e + 1];
        int2 e2 = csr[e + 2], e3 = csr[e + 3];
        float v0 = S[e0.x * 64 + lane];
        float v1 = S[e1.x * 64 + lane];
        float v2 = S[e2.x * 64 + lane];
        float v3 = S[e3.x * 64 + lane];
        acc += __int_as_float(e0.y) * v0;
        acc += __int_as_float(e1.y) * v1;
        acc += __int_as_float(e2.y) * v2;
        acc += __int_as_float(e3.y) * v3;
    }
    for (; e < end; ++e) {
        int2 ee = csr[e];
        acc += __int_as_float(ee.y) * S[ee.x * 64 + lane];
    }
    float v = acc + bias[lane];
    if (RELU) v = fmaxf(v, 0.f);
    out[(size_t)row * 64 + lane] = v;
}

// ---------------- launch ----------------

extern "C" void kernel_launch(void* const* d_in, const int* in_sizes, int n_in,
                              void* d_out, int out_size, void* d_ws, size_t ws_size,
                              hipStream_t stream) {
    const float* features = (const float*)d_in[0];
    const int*   src      = (const int*)d_in[1];
    const int*   dst      = (const int*)d_in[2];
    const float* ew       = (const float*)d_in[3];
    const float* W1       = (const float*)d_in[4];
    const float* b1       = (const float*)d_in[5];
    const float* W2       = (const float*)d_in[6];
    const float* b2       = (const float*)d_in[7];
    const float* W3       = (const float*)d_in[8];
    const float* b3       = (const float*)d_in[9];
    float*       out      = (float*)d_out;

    float* s_buf   = (float*)d_ws;                     // NN*64 f32
    float* h_buf   = s_buf + (size_t)NN * 64;          // NN*64 f32
    int*   deg     = (int*)(h_buf + (size_t)NN * 64);  // NN
    int*   offsets = deg + NN;                         // NN+4
    int*   cursor  = offsets + NN + 4;                 // NN
    int*   bsum    = cursor + NN;                      // pad to 128
    int2*  csr     = (int2*)(bsum + 128);              // NE packed records

    (void)hipMemsetAsync(deg, 0, NN * sizeof(int), stream);
    hist_kernel<<<(NE / 4 + 255) / 256, 256, 0, stream>>>(dst, deg);
    scan_pass1<<<SCAN_NB, 256, 0, stream>>>(deg, bsum);
    scan_pass2<<<1, 128, 0, stream>>>(bsum, offsets);
    scan_pass3<<<SCAN_NB, 256, 0, stream>>>(deg, bsum, offsets, cursor);

    int nchunk = (NE / 4 + 255) / 256;                 // 1563 edge chunks
    scatter_kernel<<<NWIN * nchunk, 256, 0, stream>>>(src, dst, ew, cursor, csr);

    int grid_gemm = NN / 32;
    int grid_rows = (NN + 3) / 4;
    gemm_kernel<128><<<grid_gemm, 256, 0, stream>>>(features, W1, s_buf);
    spmm_kernel<true><<<grid_rows, 256, 0, stream>>>(csr, offsets, s_buf, b1, h_buf, NN);
    gemm_kernel<64><<<grid_gemm, 256, 0, stream>>>(h_buf, W2, s_buf);
    spmm_kernel<true><<<grid_rows, 256, 0, stream>>>(csr, offsets, s_buf, b2, h_buf, NN);
    gemm_kernel<64><<<grid_gemm, 256, 0, stream>>>(h_buf, W3, s_buf);
    spmm_kernel<false><<<grid_rows, 256, 0, stream>>>(csr, offsets, s_buf, b3, out, NN);
}